// Round 1
// baseline (1532.396 us; speedup 1.0000x reference)
//
#include <hip/hip_runtime.h>
#include <hip/hip_bf16.h>

// Problem constants
#define NB   8
#define CH   512
#define CQK  64
#define HH   96
#define WW   96
#define PD   9216        // H*W
#define NEGV -1e30f

// ---------------------------------------------------------------------------
// Projection GEMM: O[n][m][p] = sum_c W[m][c] * X[n][c][p] + bias[m]
// BM = MM*16 rows, 128 cols per block, 256 threads, micro MM x 8, K step 16.
// Output cast to bf16.
// ---------------------------------------------------------------------------
template<int MM>
__global__ __launch_bounds__(256) void proj_kernel(
    const float* __restrict__ Wm, const float* __restrict__ bias,
    const float* __restrict__ X, __hip_bfloat16* __restrict__ O,
    int M, int K)
{
    constexpr int BM = MM * 16;
    __shared__ float sA[16][BM + 4];   // [k][m]
    __shared__ float sB[16][128 + 4];  // [k][p]
    const int tid = threadIdx.x;
    const int tx = tid & 15, ty = tid >> 4;
    const int m0 = blockIdx.y * BM, p0 = blockIdx.x * 128;
    const float* Xn = X + (size_t)blockIdx.z * K * PD;

    float acc[MM][8];
#pragma unroll
    for (int u = 0; u < MM; ++u)
#pragma unroll
        for (int j = 0; j < 8; ++j) acc[u][j] = 0.f;

    for (int k0 = 0; k0 < K; k0 += 16) {
#pragma unroll
        for (int r = 0; r < MM; ++r) {
            int mm = (tid >> 4) + 16 * r, kk = tid & 15;
            sA[kk][mm] = Wm[(size_t)(m0 + mm) * K + k0 + kk];
        }
#pragma unroll
        for (int r = 0; r < 8; ++r) {
            int pp = tid & 127, kk = (tid >> 7) + 2 * r;
            sB[kk][pp] = Xn[(size_t)(k0 + kk) * PD + p0 + pp];
        }
        __syncthreads();
#pragma unroll
        for (int kk = 0; kk < 16; ++kk) {
            float a[MM], b[8];
#pragma unroll
            for (int u = 0; u < MM; ++u) a[u] = sA[kk][ty * 4 + (u & 3) + (u >> 2) * 64];
#pragma unroll
            for (int j = 0; j < 8; ++j) b[j] = sB[kk][tx * 4 + (j & 3) + (j >> 2) * 64];
#pragma unroll
            for (int u = 0; u < MM; ++u)
#pragma unroll
                for (int j = 0; j < 8; ++j) acc[u][j] += a[u] * b[j];
        }
        __syncthreads();
    }
    __hip_bfloat16* On = O + (size_t)blockIdx.z * M * PD;
#pragma unroll
    for (int u = 0; u < MM; ++u) {
        int m = m0 + ty * 4 + (u & 3) + (u >> 2) * 64;
        float bs = bias[m];
#pragma unroll
        for (int j = 0; j < 8; ++j) {
            int p = p0 + tx * 4 + (j & 3) + (j >> 2) * 64;
            On[(size_t)m * PD + p] = __float2bfloat16(acc[u][j] + bs);
        }
    }
}

// ---------------------------------------------------------------------------
// Spatial transpose per (n,c) plane: out[g][x][y] = in[g][y][x], bf16.
// ---------------------------------------------------------------------------
__global__ __launch_bounds__(256) void transpose_hw_kernel(
    const __hip_bfloat16* __restrict__ in, __hip_bfloat16* __restrict__ out)
{
    __shared__ unsigned short s[96][97];
    const size_t base = (size_t)blockIdx.x * PD;
    const unsigned short* ip = (const unsigned short*)in;
    unsigned short* op = (unsigned short*)out;
    for (int idx = threadIdx.x; idx < PD; idx += 256) {
        int y = idx / 96, xx = idx - y * 96;
        s[y][xx] = ip[base + idx];
    }
    __syncthreads();
    for (int idx = threadIdx.x; idx < PD; idx += 256) {
        int xx = idx / 96, y = idx - xx * 96;
        op[base + idx] = s[y][xx];
    }
}

// ---------------------------------------------------------------------------
// e_col per (n,x): E[i][y] = sum_c k[n,c,i,x] * q[n,c,y,x]
//   reads q_t,k_t  [n][c][x][*] (contiguous); writes ecol[n][x][i][y] fp32.
// ---------------------------------------------------------------------------
__global__ __launch_bounds__(256) void ecol_kernel(
    const __hip_bfloat16* __restrict__ qt, const __hip_bfloat16* __restrict__ kt,
    float* __restrict__ ecol)
{
    const int n = blockIdx.y, xx = blockIdx.x;
    __shared__ float sK[64][96];
    __shared__ float sQ[64][96];
    for (int idx = threadIdx.x; idx < 64 * 96; idx += 256) {
        int c = idx / 96, i = idx - c * 96;
        size_t a = ((size_t)(n * 64 + c) * 96 + xx) * 96 + i;
        sK[c][i] = __bfloat162float(kt[a]);
        sQ[c][i] = __bfloat162float(qt[a]);
    }
    __syncthreads();
    const int tx = threadIdx.x & 15, ty = threadIdx.x >> 4;
    float acc[6][6] = {};
    for (int c = 0; c < 64; ++c) {
        float a[6], b[6];
#pragma unroll
        for (int u = 0; u < 6; ++u) { a[u] = sK[c][ty * 6 + u]; b[u] = sQ[c][tx * 6 + u]; }
#pragma unroll
        for (int u = 0; u < 6; ++u)
#pragma unroll
            for (int w = 0; w < 6; ++w) acc[u][w] += a[u] * b[w];
    }
    float* en = ecol + ((size_t)n * 96 + xx) * PD;
#pragma unroll
    for (int u = 0; u < 6; ++u)
#pragma unroll
        for (int w = 0; w < 6; ++w)
            en[(ty * 6 + u) * 96 + tx * 6 + w] = acc[u][w];
}

// ---------------------------------------------------------------------------
// Fused per (n,y): e_row GEMM + softmax(192) + a_col writeback + row-PV.
//   q,k,v natural layout; ecol in/out in place; row-PV result -> out (fp32).
// ---------------------------------------------------------------------------
__global__ __launch_bounds__(256) void rowattn_kernel(
    const __hip_bfloat16* __restrict__ q, const __hip_bfloat16* __restrict__ k,
    const __hip_bfloat16* __restrict__ v, float* __restrict__ ecol,
    float* __restrict__ outrow)
{
    const int n = blockIdx.y, y = blockIdx.x;
    __shared__ float sK[64][97];   // k_row [c][i]; reused as V tile
    __shared__ float sQ[64][97];   // q_row [c][x]
    __shared__ float sE[96][97];   // e_row / a_row   [i][x]
    __shared__ float sC[96][97];   // e_col / a_col   [i][x]
    const int tid = threadIdx.x;
    const int tx = tid & 15, ty = tid >> 4;

    for (int idx = tid; idx < 64 * 96; idx += 256) {
        int c = idx / 96, i = idx - c * 96;
        size_t a = ((size_t)(n * 64 + c) * 96 + y) * 96 + i;
        sK[c][i] = __bfloat162float(k[a]);
        sQ[c][i] = __bfloat162float(q[a]);
    }
    const size_t ebase = (size_t)n * 884736 + y;   // ecol[n][x][i][y]
    for (int idx = tid; idx < PD; idx += 256) {
        int xx = idx / 96, i = idx - xx * 96;
        float val = ecol[ebase + (size_t)xx * PD + i * 96];
        sC[i][xx] = (i == y) ? NEGV : val;
    }
    __syncthreads();

    // e_row[i][x] = sum_c k_row[c][i] * q_row[c][x]
    {
        float acc[6][6] = {};
        for (int c = 0; c < 64; ++c) {
            float a[6], b[6];
#pragma unroll
            for (int u = 0; u < 6; ++u) { a[u] = sK[c][ty * 6 + u]; b[u] = sQ[c][tx * 6 + u]; }
#pragma unroll
            for (int u = 0; u < 6; ++u)
#pragma unroll
                for (int w = 0; w < 6; ++w) acc[u][w] += a[u] * b[w];
        }
#pragma unroll
        for (int u = 0; u < 6; ++u)
#pragma unroll
            for (int w = 0; w < 6; ++w)
                sE[ty * 6 + u][tx * 6 + w] = acc[u][w];
    }
    __syncthreads();

    // softmax over 192 logits per x (threads 0..95)
    if (tid < 96) {
        const int xx = tid;
        float m = -1e30f;
        for (int i = 0; i < 96; ++i) m = fmaxf(m, sE[i][xx]);
        for (int i = 0; i < 96; ++i) m = fmaxf(m, sC[i][xx]);
        float ssum = 0.f;
        for (int i = 0; i < 96; ++i) { float e = __expf(sE[i][xx] - m); sE[i][xx] = e; ssum += e; }
        for (int i = 0; i < 96; ++i) {
            float val = sC[i][xx];
            float e = (val < -1e29f) ? 0.f : __expf(val - m);
            sC[i][xx] = e; ssum += e;
        }
        float inv = 1.f / ssum;
        for (int i = 0; i < 96; ++i) { sE[i][xx] *= inv; sC[i][xx] *= inv; }
    }
    __syncthreads();

    // a_col writeback (in place, same scattered addresses)
    for (int idx = tid; idx < PD; idx += 256) {
        int xx = idx / 96, i = idx - xx * 96;
        ecol[ebase + (size_t)xx * PD + i * 96] = sC[i][xx];
    }

    // row-PV: out[c][x] = sum_i v[n,c,y,i] * a_row[i][x]
    float* orow = outrow + (size_t)n * CH * PD + (size_t)y * 96;
    for (int ct = 0; ct < 8; ++ct) {
        __syncthreads();
        for (int idx = tid; idx < 64 * 96; idx += 256) {
            int c = idx / 96, i = idx - c * 96;
            sK[c][i] = __bfloat162float(v[((size_t)(n * CH + ct * 64 + c) * 96 + y) * 96 + i]);
        }
        __syncthreads();
        float acc[4][6] = {};
        for (int i = 0; i < 96; ++i) {
            float a[4], b[6];
#pragma unroll
            for (int u = 0; u < 4; ++u) a[u] = sK[ty * 4 + u][i];
#pragma unroll
            for (int w = 0; w < 6; ++w) b[w] = sE[i][tx * 6 + w];
#pragma unroll
            for (int u = 0; u < 4; ++u)
#pragma unroll
                for (int w = 0; w < 6; ++w) acc[u][w] += a[u] * b[w];
        }
#pragma unroll
        for (int u = 0; u < 4; ++u)
#pragma unroll
            for (int w = 0; w < 6; ++w)
                orow[(size_t)(ct * 64 + ty * 4 + u) * PD + tx * 6 + w] = acc[u][w];
    }
}

// ---------------------------------------------------------------------------
// col-PV per (n,x): out_col[c][y] = sum_i v[n,c,i,x] * a_col[n,i,y,x]
//   reads v_t [n][c][x][i], acol [n][x][i][y]; writes outcol [n][c][x][y] bf16.
// ---------------------------------------------------------------------------
__global__ __launch_bounds__(256) void colpv_kernel(
    const __hip_bfloat16* __restrict__ vt, const float* __restrict__ acol,
    __hip_bfloat16* __restrict__ outcol)
{
    const int n = blockIdx.y, xx = blockIdx.x;
    __shared__ float sA[96][97];   // a_col [i][y]
    __shared__ float sV[64][97];   // v_t tile [c][i]
    const int tid = threadIdx.x;
    const int tx = tid & 15, ty = tid >> 4;
    const float* an = acol + ((size_t)n * 96 + xx) * PD;
    for (int idx = tid; idx < PD; idx += 256) {
        int i = idx / 96, yy = idx - i * 96;
        sA[i][yy] = an[idx];
    }
    for (int ct = 0; ct < 8; ++ct) {
        __syncthreads();
        for (int idx = tid; idx < 64 * 96; idx += 256) {
            int c = idx / 96, i = idx - c * 96;
            sV[c][i] = __bfloat162float(vt[((size_t)(n * CH + ct * 64 + c) * 96 + xx) * 96 + i]);
        }
        __syncthreads();
        float acc[4][6] = {};
        for (int i = 0; i < 96; ++i) {
            float a[4], b[6];
#pragma unroll
            for (int u = 0; u < 4; ++u) a[u] = sV[ty * 4 + u][i];
#pragma unroll
            for (int w = 0; w < 6; ++w) b[w] = sA[i][tx * 6 + w];
#pragma unroll
            for (int u = 0; u < 4; ++u)
#pragma unroll
                for (int w = 0; w < 6; ++w) acc[u][w] += a[u] * b[w];
        }
#pragma unroll
        for (int u = 0; u < 4; ++u)
#pragma unroll
            for (int w = 0; w < 6; ++w)
                outcol[((size_t)(n * CH + ct * 64 + ty * 4 + u) * 96 + xx) * 96 + tx * 6 + w] =
                    __float2bfloat16(acc[u][w]);
    }
}

// ---------------------------------------------------------------------------
// merge per (n,c): out = gamma*(row + col^T) + x
// ---------------------------------------------------------------------------
__global__ __launch_bounds__(256) void merge_kernel(
    const __hip_bfloat16* __restrict__ outcol, const float* __restrict__ xin,
    const float* __restrict__ gamma_p, float* __restrict__ out)
{
    __shared__ float s[96][97];
    const size_t base = (size_t)blockIdx.x * PD;
    const float g = gamma_p[0];
    for (int idx = threadIdx.x; idx < PD; idx += 256) {
        int xr = idx / 96, yr = idx - xr * 96;
        s[xr][yr] = __bfloat162float(outcol[base + idx]);
    }
    __syncthreads();
    for (int idx = threadIdx.x; idx < PD; idx += 256) {
        int yy = idx / 96, xw = idx - yy * 96;
        out[base + idx] = g * (out[base + idx] + s[xw][yy]) + xin[base + idx];
    }
}

// ---------------------------------------------------------------------------
extern "C" void kernel_launch(void* const* d_in, const int* in_sizes, int n_in,
                              void* d_out, int out_size, void* d_ws, size_t ws_size,
                              hipStream_t stream)
{
    const float* x     = (const float*)d_in[0];
    const float* wq    = (const float*)d_in[1];
    const float* bq    = (const float*)d_in[2];
    const float* wk    = (const float*)d_in[3];
    const float* bk    = (const float*)d_in[4];
    const float* wv    = (const float*)d_in[5];
    const float* bv    = (const float*)d_in[6];
    const float* gamma = (const float*)d_in[7];
    float* out = (float*)d_out;

    char* ws = (char*)d_ws;
    const size_t szQK = (size_t)NB * CQK * PD * 2;  //  9,437,184 B
    const size_t szV  = (size_t)NB * CH  * PD * 2;  // 75,497,472 B
    __hip_bfloat16* qb  = (__hip_bfloat16*)(ws);
    __hip_bfloat16* kb  = (__hip_bfloat16*)(ws + szQK);
    __hip_bfloat16* qtb = (__hip_bfloat16*)(ws + 2 * szQK);
    __hip_bfloat16* ktb = (__hip_bfloat16*)(ws + 3 * szQK);
    __hip_bfloat16* vb  = (__hip_bfloat16*)(ws + 4 * szQK);          // later: outcol
    __hip_bfloat16* vtb = (__hip_bfloat16*)(ws + 4 * szQK + szV);
    float*          ecol = (float*)(ws + 4 * szQK + 2 * szV);        // 28,311,552 B

    dim3 blk(256);
    // 1) projections (fp32 compute, bf16 store)
    proj_kernel<4><<<dim3(72, 1, NB), blk, 0, stream>>>(wq, bq, x, qb, CQK, CH);
    proj_kernel<4><<<dim3(72, 1, NB), blk, 0, stream>>>(wk, bk, x, kb, CQK, CH);
    proj_kernel<8><<<dim3(72, 4, NB), blk, 0, stream>>>(wv, bv, x, vb, CH, CH);
    // 2) spatial transposes
    transpose_hw_kernel<<<dim3(NB * CQK), blk, 0, stream>>>(qb, qtb);
    transpose_hw_kernel<<<dim3(NB * CQK), blk, 0, stream>>>(kb, ktb);
    transpose_hw_kernel<<<dim3(NB * CH),  blk, 0, stream>>>(vb, vtb);
    // 3) e_col
    ecol_kernel<<<dim3(WW, NB), blk, 0, stream>>>(qtb, ktb, ecol);
    // 4) e_row + softmax + a_col writeback + row-PV
    rowattn_kernel<<<dim3(HH, NB), blk, 0, stream>>>(qb, kb, vb, ecol, out);
    // 5) col-PV (outcol aliases vb — v no longer needed)
    colpv_kernel<<<dim3(WW, NB), blk, 0, stream>>>(vtb, ecol, vb);
    // 6) merge
    merge_kernel<<<dim3(NB * CH), blk, 0, stream>>>(vb, x, gamma, out);
}

// Round 3
// 1061.255 us; speedup vs baseline: 1.4439x; 1.4439x over previous
//
#include <hip/hip_runtime.h>
#include <hip/hip_bf16.h>

// Problem constants
#define NB   8
#define CH   512
#define CQK  64
#define HH   96
#define WW   96
#define PD   9216        // H*W
#define NEGV -1e30f

typedef __attribute__((ext_vector_type(8))) short bf16x8;
typedef __attribute__((ext_vector_type(4))) float f32x4;
typedef __attribute__((ext_vector_type(4))) unsigned short u16x4;

__device__ __forceinline__ unsigned short f2bf(float f) {
    __hip_bfloat16 h = __float2bfloat16(f);
    return *(unsigned short*)&h;
}

__device__ __forceinline__ void gload_lds16(const void* g, void* l) {
    __builtin_amdgcn_global_load_lds((const __attribute__((address_space(1))) void*)g,
                                     (__attribute__((address_space(3))) void*)l, 16, 0, 0);
}

// ---------------------------------------------------------------------------
// Pack W = [wq;wk;wv] -> bf16 Wall[640][512], biases -> Ball[640] fp32.
// ---------------------------------------------------------------------------
__global__ __launch_bounds__(256) void pack_w_kernel(
    const float* __restrict__ wq, const float* __restrict__ bq,
    const float* __restrict__ wk, const float* __restrict__ bk,
    const float* __restrict__ wv, const float* __restrict__ bv,
    unsigned short* __restrict__ Wall, float* __restrict__ Ball)
{
    int idx = blockIdx.x * 256 + threadIdx.x;          // 640*256 threads
    int row = idx >> 8, col2 = (idx & 255) * 2;
    const float* src = (row < 64) ? (wq + (size_t)row * CH)
                     : (row < 128) ? (wk + (size_t)(row - 64) * CH)
                                   : (wv + (size_t)(row - 128) * CH);
    unsigned int pk = (unsigned int)f2bf(src[col2]) | ((unsigned int)f2bf(src[col2 + 1]) << 16);
    *(unsigned int*)(Wall + (size_t)row * CH + col2) = pk;
    if (idx < 640)
        Ball[idx] = (idx < 64) ? bq[idx] : (idx < 128) ? bk[idx - 64] : bv[idx - 128];
}

// ---------------------------------------------------------------------------
// Cast + transpose: Xt[n][p][c] (bf16) from x[n][c][p] (fp32). 64x64 tiles.
// ---------------------------------------------------------------------------
__global__ __launch_bounds__(256) void cast_xt_kernel(
    const float* __restrict__ x, unsigned short* __restrict__ Xt)
{
    __shared__ float s[64][65];
    const int nb = blockIdx.z;
    const int c0 = blockIdx.y * 64;
    const int p0 = blockIdx.x * 64;
    const float* xn = x + (size_t)nb * CH * PD;
    for (int t = threadIdx.x; t < 4096; t += 256) {
        int c = t >> 6, p = t & 63;
        s[c][p] = xn[(size_t)(c0 + c) * PD + p0 + p];
    }
    __syncthreads();
    unsigned short* Xn = Xt + (size_t)nb * PD * CH;
    for (int t = threadIdx.x; t < 2048; t += 256) {
        int pp = t >> 5, cc = (t & 31) * 2;
        unsigned int pk = (unsigned int)f2bf(s[cc][pp]) | ((unsigned int)f2bf(s[cc + 1][pp]) << 16);
        *(unsigned int*)(Xn + (size_t)(p0 + pp) * CH + c0 + cc) = pk;
    }
}

// ---------------------------------------------------------------------------
// MFMA projection: O^T[p][mj] = sum_c Xt[p][c] * Wall[mj][c]  (+Ball[mj])
// 128(p) x 128(mj) tile, 4 waves, each 64x64 via 4x4 frags of 16x16x32 bf16.
// Epilogue routes mj -> q / k / v in [n][m][p] bf16 layout.
// ---------------------------------------------------------------------------
__global__ __launch_bounds__(256) void proj_mfma_kernel(
    const unsigned short* __restrict__ Xt, const unsigned short* __restrict__ Wall,
    const float* __restrict__ Ball,
    unsigned short* __restrict__ qb, unsigned short* __restrict__ kb,
    unsigned short* __restrict__ vb)
{
    __shared__ unsigned short sA[4096];   // [128 p][32 k]
    __shared__ unsigned short sB[4096];   // [128 m][32 k]
    const int tid  = threadIdx.x;
    const int lane = tid & 63, wv = tid >> 6;
    const int wr = wv >> 1, wc = wv & 1;
    const int p0 = blockIdx.x * 128;
    const int n0 = blockIdx.y * 128;
    const int nb = blockIdx.z;
    const unsigned short* Xn = Xt + (size_t)nb * PD * CH;

    f32x4 acc[4][4];
#pragma unroll
    for (int i = 0; i < 4; ++i)
#pragma unroll
        for (int j = 0; j < 4; ++j) acc[i][j] = (f32x4){0.f, 0.f, 0.f, 0.f};

    for (int k0 = 0; k0 < CH; k0 += 32) {
#pragma unroll
        for (int t = 0; t < 2; ++t) {
            int s = t * 256 + wv * 64 + lane;
            int r = s >> 2, j = s & 3;
            gload_lds16(Xn + (size_t)(p0 + r) * CH + k0 + j * 8,
                        sA + (size_t)(t * 256 + wv * 64) * 8);
            gload_lds16(Wall + (size_t)(n0 + r) * CH + k0 + j * 8,
                        sB + (size_t)(t * 256 + wv * 64) * 8);
        }
        __syncthreads();

        const int ra = (lane & 15), kg = lane >> 4;
        bf16x8 af[4], bfr[4];
#pragma unroll
        for (int f = 0; f < 4; ++f) {
            af[f]  = *(const bf16x8*)&sA[(wr * 64 + f * 16 + ra) * 32 + kg * 8];
            bfr[f] = *(const bf16x8*)&sB[(wc * 64 + f * 16 + ra) * 32 + kg * 8];
        }
#pragma unroll
        for (int fm = 0; fm < 4; ++fm)
#pragma unroll
            for (int fn = 0; fn < 4; ++fn)
                acc[fm][fn] = __builtin_amdgcn_mfma_f32_16x16x32_bf16(
                    af[fm], bfr[fn], acc[fm][fn], 0, 0, 0);
        __syncthreads();
    }

    const int lj = lane & 15, li4 = (lane >> 4) * 4;
#pragma unroll
    for (int fm = 0; fm < 4; ++fm) {
        int prow = p0 + wr * 64 + fm * 16 + li4;
#pragma unroll
        for (int fn = 0; fn < 4; ++fn) {
            int mj = n0 + wc * 64 + fn * 16 + lj;
            float bs = Ball[mj];
            unsigned short* dst;
            if (mj < 64)       dst = qb + ((size_t)nb * CQK + mj) * PD + prow;
            else if (mj < 128) dst = kb + ((size_t)nb * CQK + (mj - 64)) * PD + prow;
            else               dst = vb + ((size_t)nb * CH + (mj - 128)) * PD + prow;
            u16x4 pk;
#pragma unroll
            for (int r = 0; r < 4; ++r) pk[r] = f2bf(acc[fm][fn][r] + bs);
            *(u16x4*)dst = pk;
        }
    }
}

// ---------------------------------------------------------------------------
// Spatial transpose per (n,c) plane: out[g][x][y] = in[g][y][x], bf16.
// ---------------------------------------------------------------------------
__global__ __launch_bounds__(256) void transpose_hw_kernel(
    const __hip_bfloat16* __restrict__ in, __hip_bfloat16* __restrict__ out)
{
    __shared__ unsigned short s[96][97];
    const size_t base = (size_t)blockIdx.x * PD;
    const unsigned short* ip = (const unsigned short*)in;
    unsigned short* op = (unsigned short*)out;
    for (int idx = threadIdx.x; idx < PD; idx += 256) {
        int y = idx / 96, xx = idx - y * 96;
        s[y][xx] = ip[base + idx];
    }
    __syncthreads();
    for (int idx = threadIdx.x; idx < PD; idx += 256) {
        int xx = idx / 96, y = idx - xx * 96;
        op[base + idx] = s[y][xx];
    }
}

// ---------------------------------------------------------------------------
// e_col per (n,x): E[i][y] = sum_c k[n,c,i,x] * q[n,c,y,x]
// ---------------------------------------------------------------------------
__global__ __launch_bounds__(256) void ecol_kernel(
    const __hip_bfloat16* __restrict__ qt, const __hip_bfloat16* __restrict__ kt,
    float* __restrict__ ecol)
{
    const int n = blockIdx.y, xx = blockIdx.x;
    __shared__ float sK[64][96];
    __shared__ float sQ[64][96];
    for (int idx = threadIdx.x; idx < 64 * 96; idx += 256) {
        int c = idx / 96, i = idx - c * 96;
        size_t a = ((size_t)(n * 64 + c) * 96 + xx) * 96 + i;
        sK[c][i] = __bfloat162float(kt[a]);
        sQ[c][i] = __bfloat162float(qt[a]);
    }
    __syncthreads();
    const int tx = threadIdx.x & 15, ty = threadIdx.x >> 4;
    float acc[6][6] = {};
    for (int c = 0; c < 64; ++c) {
        float a[6], b[6];
#pragma unroll
        for (int u = 0; u < 6; ++u) { a[u] = sK[c][ty * 6 + u]; b[u] = sQ[c][tx * 6 + u]; }
#pragma unroll
        for (int u = 0; u < 6; ++u)
#pragma unroll
            for (int w = 0; w < 6; ++w) acc[u][w] += a[u] * b[w];
    }
    float* en = ecol + ((size_t)n * 96 + xx) * PD;
#pragma unroll
    for (int u = 0; u < 6; ++u)
#pragma unroll
        for (int w = 0; w < 6; ++w)
            en[(ty * 6 + u) * 96 + tx * 6 + w] = acc[u][w];
}

// ---------------------------------------------------------------------------
// Fused per (n,y): e_row GEMM + softmax(192) + a_col writeback + row-PV.
// ---------------------------------------------------------------------------
__global__ __launch_bounds__(256) void rowattn_kernel(
    const __hip_bfloat16* __restrict__ q, const __hip_bfloat16* __restrict__ k,
    const __hip_bfloat16* __restrict__ v, float* __restrict__ ecol,
    float* __restrict__ outrow)
{
    const int n = blockIdx.y, y = blockIdx.x;
    __shared__ float sK[64][97];   // k_row [c][i]; reused as V tile
    __shared__ float sQ[64][97];   // q_row [c][x]
    __shared__ float sE[96][97];   // e_row / a_row   [i][x]
    __shared__ float sC[96][97];   // e_col / a_col   [i][x]
    const int tid = threadIdx.x;
    const int tx = tid & 15, ty = tid >> 4;

    for (int idx = tid; idx < 64 * 96; idx += 256) {
        int c = idx / 96, i = idx - c * 96;
        size_t a = ((size_t)(n * 64 + c) * 96 + y) * 96 + i;
        sK[c][i] = __bfloat162float(k[a]);
        sQ[c][i] = __bfloat162float(q[a]);
    }
    const size_t ebase = (size_t)n * 884736 + y;   // ecol[n][x][i][y]
    for (int idx = tid; idx < PD; idx += 256) {
        int xx = idx / 96, i = idx - xx * 96;
        float val = ecol[ebase + (size_t)xx * PD + i * 96];
        sC[i][xx] = (i == y) ? NEGV : val;
    }
    __syncthreads();

    {
        float acc[6][6] = {};
        for (int c = 0; c < 64; ++c) {
            float a[6], b[6];
#pragma unroll
            for (int u = 0; u < 6; ++u) { a[u] = sK[c][ty * 6 + u]; b[u] = sQ[c][tx * 6 + u]; }
#pragma unroll
            for (int u = 0; u < 6; ++u)
#pragma unroll
                for (int w = 0; w < 6; ++w) acc[u][w] += a[u] * b[w];
        }
#pragma unroll
        for (int u = 0; u < 6; ++u)
#pragma unroll
            for (int w = 0; w < 6; ++w)
                sE[ty * 6 + u][tx * 6 + w] = acc[u][w];
    }
    __syncthreads();

    if (tid < 96) {
        const int xx = tid;
        float m = -1e30f;
        for (int i = 0; i < 96; ++i) m = fmaxf(m, sE[i][xx]);
        for (int i = 0; i < 96; ++i) m = fmaxf(m, sC[i][xx]);
        float ssum = 0.f;
        for (int i = 0; i < 96; ++i) { float e = __expf(sE[i][xx] - m); sE[i][xx] = e; ssum += e; }
        for (int i = 0; i < 96; ++i) {
            float val = sC[i][xx];
            float e = (val < -1e29f) ? 0.f : __expf(val - m);
            sC[i][xx] = e; ssum += e;
        }
        float inv = 1.f / ssum;
        for (int i = 0; i < 96; ++i) { sE[i][xx] *= inv; sC[i][xx] *= inv; }
    }
    __syncthreads();

    for (int idx = tid; idx < PD; idx += 256) {
        int xx = idx / 96, i = idx - xx * 96;
        ecol[ebase + (size_t)xx * PD + i * 96] = sC[i][xx];
    }

    float* orow = outrow + (size_t)n * CH * PD + (size_t)y * 96;
    for (int ct = 0; ct < 8; ++ct) {
        __syncthreads();
        for (int idx = tid; idx < 64 * 96; idx += 256) {
            int c = idx / 96, i = idx - c * 96;
            sK[c][i] = __bfloat162float(v[((size_t)(n * CH + ct * 64 + c) * 96 + y) * 96 + i]);
        }
        __syncthreads();
        float acc[4][6] = {};
        for (int i = 0; i < 96; ++i) {
            float a[4], b[6];
#pragma unroll
            for (int u = 0; u < 4; ++u) a[u] = sK[ty * 4 + u][i];
#pragma unroll
            for (int w = 0; w < 6; ++w) b[w] = sE[i][tx * 6 + w];
#pragma unroll
            for (int u = 0; u < 4; ++u)
#pragma unroll
                for (int w = 0; w < 6; ++w) acc[u][w] += a[u] * b[w];
        }
#pragma unroll
        for (int u = 0; u < 4; ++u)
#pragma unroll
            for (int w = 0; w < 6; ++w)
                orow[(size_t)(ct * 64 + ty * 4 + u) * PD + tx * 6 + w] = acc[u][w];
    }
}

// ---------------------------------------------------------------------------
// col-PV per (n,x): out_col[c][y] = sum_i v[n,c,i,x] * a_col[n,i,y,x]
// ---------------------------------------------------------------------------
__global__ __launch_bounds__(256) void colpv_kernel(
    const __hip_bfloat16* __restrict__ vt, const float* __restrict__ acol,
    __hip_bfloat16* __restrict__ outcol)
{
    const int n = blockIdx.y, xx = blockIdx.x;
    __shared__ float sA[96][97];
    __shared__ float sV[64][97];
    const int tid = threadIdx.x;
    const int tx = tid & 15, ty = tid >> 4;
    const float* an = acol + ((size_t)n * 96 + xx) * PD;
    for (int idx = tid; idx < PD; idx += 256) {
        int i = idx / 96, yy = idx - i * 96;
        sA[i][yy] = an[idx];
    }
    for (int ct = 0; ct < 8; ++ct) {
        __syncthreads();
        for (int idx = tid; idx < 64 * 96; idx += 256) {
            int c = idx / 96, i = idx - c * 96;
            sV[c][i] = __bfloat162float(vt[((size_t)(n * CH + ct * 64 + c) * 96 + xx) * 96 + i]);
        }
        __syncthreads();
        float acc[4][6] = {};
        for (int i = 0; i < 96; ++i) {
            float a[4], b[6];
#pragma unroll
            for (int u = 0; u < 4; ++u) a[u] = sV[ty * 4 + u][i];
#pragma unroll
            for (int w = 0; w < 6; ++w) b[w] = sA[i][tx * 6 + w];
#pragma unroll
            for (int u = 0; u < 4; ++u)
#pragma unroll
                for (int w = 0; w < 6; ++w) acc[u][w] += a[u] * b[w];
        }
#pragma unroll
        for (int u = 0; u < 4; ++u)
#pragma unroll
            for (int w = 0; w < 6; ++w)
                outcol[((size_t)(n * CH + ct * 64 + ty * 4 + u) * 96 + xx) * 96 + tx * 6 + w] =
                    __float2bfloat16(acc[u][w]);
    }
}

// ---------------------------------------------------------------------------
// merge per (n,c): out = gamma*(row + col^T) + x
// ---------------------------------------------------------------------------
__global__ __launch_bounds__(256) void merge_kernel(
    const __hip_bfloat16* __restrict__ outcol, const float* __restrict__ xin,
    const float* __restrict__ gamma_p, float* __restrict__ out)
{
    __shared__ float s[96][97];
    const size_t base = (size_t)blockIdx.x * PD;
    const float g = gamma_p[0];
    for (int idx = threadIdx.x; idx < PD; idx += 256) {
        int xr = idx / 96, yr = idx - xr * 96;
        s[xr][yr] = __bfloat162float(outcol[base + idx]);
    }
    __syncthreads();
    for (int idx = threadIdx.x; idx < PD; idx += 256) {
        int yy = idx / 96, xw = idx - yy * 96;
        out[base + idx] = g * (out[base + idx] + s[xw][yy]) + xin[base + idx];
    }
}

// ---------------------------------------------------------------------------
extern "C" void kernel_launch(void* const* d_in, const int* in_sizes, int n_in,
                              void* d_out, int out_size, void* d_ws, size_t ws_size,
                              hipStream_t stream)
{
    const float* x     = (const float*)d_in[0];
    const float* wq    = (const float*)d_in[1];
    const float* bq    = (const float*)d_in[2];
    const float* wk    = (const float*)d_in[3];
    const float* bk    = (const float*)d_in[4];
    const float* wv    = (const float*)d_in[5];
    const float* bv    = (const float*)d_in[6];
    const float* gamma = (const float*)d_in[7];
    float* out = (float*)d_out;

    char* ws = (char*)d_ws;
    const size_t szQK = (size_t)NB * CQK * PD * 2;  //  9,437,184 B
    const size_t szV  = (size_t)NB * CH  * PD * 2;  // 75,497,472 B
    __hip_bfloat16* qb  = (__hip_bfloat16*)(ws);
    __hip_bfloat16* kb  = (__hip_bfloat16*)(ws + szQK);
    __hip_bfloat16* qtb = (__hip_bfloat16*)(ws + 2 * szQK);
    __hip_bfloat16* ktb = (__hip_bfloat16*)(ws + 3 * szQK);
    __hip_bfloat16* vb  = (__hip_bfloat16*)(ws + 4 * szQK);          // later: outcol
    __hip_bfloat16* vtb = (__hip_bfloat16*)(ws + 4 * szQK + szV);
    float*          ecol = (float*)(ws + 4 * szQK + 2 * szV);        // 28,311,552 B
    // aliases (overwritten after proj_mfma completes):
    unsigned short* Wall = (unsigned short*)qtb;                      // 0.66 MB < 9.4 MB
    float*          Ball = (float*)(ws + 2 * szQK + 2 * 1024 * 1024); // inside qtb region
    unsigned short* Xt   = (unsigned short*)vtb;                      // same size as vtb

    dim3 blk(256);
    // 1) pack weights + bias (bf16)
    pack_w_kernel<<<dim3(640), blk, 0, stream>>>(wq, bq, wk, bk, wv, bv, Wall, Ball);
    // 2) cast + transpose x -> Xt[n][p][c] bf16
    cast_xt_kernel<<<dim3(144, 8, NB), blk, 0, stream>>>(x, Xt);
    // 3) fused q/k/v projection via MFMA
    proj_mfma_kernel<<<dim3(72, 5, NB), blk, 0, stream>>>(
        Xt, Wall, Ball, (unsigned short*)qb, (unsigned short*)kb, (unsigned short*)vb);
    // 4) spatial transposes (overwrite Wall/Ball/Xt regions — proj done by then)
    transpose_hw_kernel<<<dim3(NB * CQK), blk, 0, stream>>>(qb, qtb);
    transpose_hw_kernel<<<dim3(NB * CQK), blk, 0, stream>>>(kb, ktb);
    transpose_hw_kernel<<<dim3(NB * CH),  blk, 0, stream>>>(vb, vtb);
    // 5) e_col
    ecol_kernel<<<dim3(WW, NB), blk, 0, stream>>>(qtb, ktb, ecol);
    // 6) e_row + softmax + a_col writeback + row-PV
    rowattn_kernel<<<dim3(HH, NB), blk, 0, stream>>>(qb, kb, vb, ecol, out);
    // 7) col-PV (outcol aliases vb — v no longer needed)
    colpv_kernel<<<dim3(WW, NB), blk, 0, stream>>>(vtb, ecol, vb);
    // 8) merge
    merge_kernel<<<dim3(NB * CH), blk, 0, stream>>>(vb, x, gamma, out);
}